// Round 5
// baseline (412.664 us; speedup 1.0000x reference)
//
#include <hip/hip_runtime.h>
#include <hip/hip_fp16.h>
#include <math.h>

// GCNConv QNet: out = tanh( (segsum(x[src]*norm, dst) + selfloop) @ W1 + b1 ) @ W2 + b2
// norm = dinv[src]*dinv[dst], dinv = rsqrt(in_degree + 1).
// Aggregation in 32-dim obs space (W1 applied AFTER segment_sum — linearity).
// R5: multisplit by dst-bucket (R4) + fp16 prescaled y = x*dinv (kills the
// per-entry dinv gather, halves row bytes) + high-concurrency quarter-wave
// gather (16 gathers in flight/wave) into LDS accumulators.

#define NOBS 32
#define NMID 64
#define NACT 8
#define BSH 7
#define BNODES 128           // nodes per bucket
#define CAP 4096             // max entries per bucket (mean ~2048)
#define ARENA_B 16384        // bytes per bucket arena (= CAP*4 = BNODES*NOBS*4)
#define SPLIT_E 4096         // edges per split block

__device__ __forceinline__ bool edges_i64(const int* ei) {
    return (ei[1] | ei[3] | ei[5] | ei[7]) == 0;
}

__global__ void k_zero(int* __restrict__ p, int n) {
    int i = blockIdx.x * blockDim.x + threadIdx.x;
    if (i < n) p[i] = 0;
}

// Multisplit: group 4096 edges by bucket in LDS, flush contiguous runs.
__global__ __launch_bounds__(256) void k_split(
        const int* __restrict__ ei, int* __restrict__ gcnt,
        unsigned int* __restrict__ arena, long long e, int nbuckets) {
    __shared__ int ebuf[SPLIT_E];             // packed entries (16 KB)
    __shared__ unsigned short bbuf[SPLIT_E];  // bucket ids (8 KB)
    __shared__ int sbuf[SPLIT_E];             // bucket-grouped entries (16 KB)
    __shared__ int offs[1024];
    __shared__ int cur[1024];
    __shared__ int tsum[256];
    const int tid = threadIdx.x;

    for (int b = tid; b < 1024; b += 256) cur[b] = 0;  // cur = hist
    __syncthreads();

    const long long base = (long long)blockIdx.x * SPLIT_E;
    const bool i64 = edges_i64(ei);
    const long long* e64 = (const long long*)ei;
    for (int k = tid; k < SPLIT_E; k += 256) {
        long long ge = base + k;
        if (ge < e) {
            int s, d;
            if (i64) { s = (int)e64[ge]; d = (int)e64[e + ge]; }
            else     { s = ei[ge];       d = ei[e + ge]; }
            ebuf[k] = s | ((d & (BNODES - 1)) << 20);
            int b = d >> BSH;
            bbuf[k] = (unsigned short)b;
            atomicAdd(&cur[b], 1);
        } else {
            bbuf[k] = 0xFFFFu;
        }
    }
    __syncthreads();

    // exclusive scan of cur(=hist)[0..1024), 4 bins/thread
    const int t4 = tid * 4;
    int s0 = cur[t4], s1 = cur[t4 + 1], s2 = cur[t4 + 2], s3 = cur[t4 + 3];
    int my = s0 + s1 + s2 + s3;
    tsum[tid] = my;
    __syncthreads();
    for (int off = 1; off < 256; off <<= 1) {
        int t = (tid >= off) ? tsum[tid - off] : 0;
        __syncthreads();
        tsum[tid] += t;
        __syncthreads();
    }
    int ex = tsum[tid] - my;
    offs[t4] = ex;
    offs[t4 + 1] = ex + s0;
    offs[t4 + 2] = ex + s0 + s1;
    offs[t4 + 3] = ex + s0 + s1 + s2;
    __syncthreads();
    for (int b = tid; b < 1024; b += 256) cur[b] = offs[b];  // cursors
    __syncthreads();

    // group into sbuf
    for (int k = tid; k < SPLIT_E; k += 256) {
        int b = bbuf[k];
        if (b != 0xFFFF) {
            int slot = atomicAdd(&cur[b], 1);
            sbuf[slot] = ebuf[k];
        }
    }
    __syncthreads();

    // flush one run per thread (contiguous addresses -> L2 line merge)
    for (int b = tid; b < nbuckets; b += 256) {
        int beg = offs[b];
        int len = cur[b] - beg;
        if (len <= 0) continue;
        int g = atomicAdd(&gcnt[b], len);
        if (g >= CAP) continue;
        if (g + len > CAP) len = CAP - g;
        unsigned int* dst = arena + (size_t)b * CAP + g;
        for (int j = 0; j < len; ++j) dst[j] = (unsigned int)sbuf[beg + j];
    }
}

// Per-bucket in-degree -> dinv
__global__ __launch_bounds__(256) void k_dinv(
        const unsigned int* __restrict__ arena, const int* __restrict__ gcnt,
        float* __restrict__ dinv, int n) {
    __shared__ int cnt[BNODES];
    const int b = blockIdx.x, tid = threadIdx.x;
    if (tid < BNODES) cnt[tid] = 0;
    __syncthreads();
    int count = min(gcnt[b], CAP);
    const unsigned int* ent = arena + (size_t)b * CAP;
    for (int p = tid; p < count; p += 256)
        atomicAdd(&cnt[ent[p] >> 20], 1);
    __syncthreads();
    int node = b * BNODES + tid;
    if (tid < BNODES && node < n)
        dinv[node] = rsqrtf((float)(cnt[tid] + 1));
}

// Prescale: y[i][c] = x[i][c] * dinv[i], fp16. 2 channels per thread.
__global__ void k_y(const float* __restrict__ x, const float* __restrict__ dinv,
                    __half2* __restrict__ y2, int n) {
    long long t = (long long)blockIdx.x * blockDim.x + threadIdx.x;  // over n*16
    if (t >= (long long)n * (NOBS / 2)) return;
    int i = (int)(t >> 4);
    float di = dinv[i];
    float2 v = ((const float2*)x)[t];
    y2[t] = __floats2half2_rn(v.x * di, v.y * di);
}

// Per-bucket aggregation: quarter-wave (16 lanes) per entry, each lane 2
// channels via half2; unroll 4 -> 16 gathers in flight per wave.
// Overwrites the consumed arena with agg rows.
__global__ __launch_bounds__(512) void k_agg(
        const int* __restrict__ gcnt, const float* __restrict__ dinv,
        const __half2* __restrict__ y2, char* __restrict__ arena_c, int n) {
    __shared__ float acc[BNODES * NOBS];  // 16 KB
    const int b = blockIdx.x, tid = threadIdx.x;
    for (int i = tid; i < BNODES * NOBS; i += 512) acc[i] = 0.f;
    __syncthreads();

    const unsigned int* ent = (const unsigned int*)(arena_c + (size_t)b * ARENA_B);
    const int count = min(gcnt[b], CAP);
    const int qw = tid >> 4;        // quarter-wave 0..31
    const int l = tid & 15;         // lane in quarter-wave
    const int c2 = l * 2;

    int p = qw;
    for (; p + 96 < count; p += 128) {
        unsigned int e0 = ent[p], e1 = ent[p + 32], e2 = ent[p + 64], e3 = ent[p + 96];
        float2 v0 = __half22float2(y2[(size_t)(e0 & 0xFFFFF) * 16 + l]);
        float2 v1 = __half22float2(y2[(size_t)(e1 & 0xFFFFF) * 16 + l]);
        float2 v2 = __half22float2(y2[(size_t)(e2 & 0xFFFFF) * 16 + l]);
        float2 v3 = __half22float2(y2[(size_t)(e3 & 0xFFFFF) * 16 + l]);
        atomicAdd(&acc[(e0 >> 20) * NOBS + c2], v0.x);
        atomicAdd(&acc[(e0 >> 20) * NOBS + c2 + 1], v0.y);
        atomicAdd(&acc[(e1 >> 20) * NOBS + c2], v1.x);
        atomicAdd(&acc[(e1 >> 20) * NOBS + c2 + 1], v1.y);
        atomicAdd(&acc[(e2 >> 20) * NOBS + c2], v2.x);
        atomicAdd(&acc[(e2 >> 20) * NOBS + c2 + 1], v2.y);
        atomicAdd(&acc[(e3 >> 20) * NOBS + c2], v3.x);
        atomicAdd(&acc[(e3 >> 20) * NOBS + c2 + 1], v3.y);
    }
    for (; p < count; p += 32) {
        unsigned int e0 = ent[p];
        float2 v0 = __half22float2(y2[(size_t)(e0 & 0xFFFFF) * 16 + l]);
        atomicAdd(&acc[(e0 >> 20) * NOBS + c2], v0.x);
        atomicAdd(&acc[(e0 >> 20) * NOBS + c2 + 1], v0.y);
    }
    __syncthreads();

    // epilogue: agg_row = (acc + y_self) * dinv_i, overwrite arena
    float2* aggout = (float2*)(arena_c + (size_t)b * ARENA_B);
    for (int idx = tid; idx < BNODES * (NOBS / 2); idx += 512) {
        int row = idx >> 4, ll = idx & 15;
        int node = b * BNODES + row;
        if (node >= n) break;
        float di = dinv[node];
        float2 s = __half22float2(y2[(size_t)node * 16 + ll]);
        float2 o;
        o.x = (acc[row * NOBS + ll * 2] + s.x) * di;
        o.y = (acc[row * NOBS + ll * 2 + 1] + s.y) * di;
        aggout[idx] = o;
    }
}

// Per-node dense epilogue: out = tanh(agg @ W1 + b1) @ W2 + b2.
// agg rows live in the bucket arenas (stride ARENA_B per 128 nodes).
__global__ __launch_bounds__(256) void k_final(
        const char* __restrict__ arena_c, const float* __restrict__ W1,
        const float* __restrict__ b1, const float* __restrict__ W2,
        const float* __restrict__ b2, float* __restrict__ out, int n) {
    __shared__ float sW1T[NMID * NOBS];  // sW1T[j*32+c] = W1[c][j]
    __shared__ float sW2[NMID * NACT];
    __shared__ float sb1[NMID];
    __shared__ float sb2[NACT];
    for (int t = threadIdx.x; t < NMID * NOBS; t += 256) {
        int j = t >> 5, c = t & 31;
        sW1T[t] = W1[c * NMID + j];
    }
    for (int t = threadIdx.x; t < NMID * NACT; t += 256) sW2[t] = W2[t];
    if (threadIdx.x < NMID) sb1[threadIdx.x] = b1[threadIdx.x];
    if (threadIdx.x < NACT) sb2[threadIdx.x] = b2[threadIdx.x];
    __syncthreads();

    int i = blockIdx.x * 256 + threadIdx.x;
    if (i >= n) return;

    const float* arow = (const float*)(arena_c + (size_t)(i >> BSH) * ARENA_B)
                        + (size_t)(i & (BNODES - 1)) * NOBS;
    const float4* a4 = (const float4*)arow;
    float4 A0 = a4[0], A1 = a4[1], A2 = a4[2], A3 = a4[3];
    float4 A4 = a4[4], A5 = a4[5], A6 = a4[6], A7 = a4[7];

    float4 oa = *(const float4*)(sb2);
    float4 ob = *(const float4*)(sb2 + 4);

    for (int j = 0; j < NMID; ++j) {
        const float4* w = (const float4*)(sW1T + j * NOBS);
        float4 w0 = w[0], w1 = w[1], w2 = w[2], w3 = w[3];
        float4 w4 = w[4], w5 = w[5], w6 = w[6], w7 = w[7];
        float ma = sb1[j], mb = 0.f, mc = 0.f, md = 0.f;
        ma = fmaf(A0.x, w0.x, ma); ma = fmaf(A0.y, w0.y, ma);
        ma = fmaf(A0.z, w0.z, ma); ma = fmaf(A0.w, w0.w, ma);
        mb = fmaf(A1.x, w1.x, mb); mb = fmaf(A1.y, w1.y, mb);
        mb = fmaf(A1.z, w1.z, mb); mb = fmaf(A1.w, w1.w, mb);
        mc = fmaf(A2.x, w2.x, mc); mc = fmaf(A2.y, w2.y, mc);
        mc = fmaf(A2.z, w2.z, mc); mc = fmaf(A2.w, w2.w, mc);
        md = fmaf(A3.x, w3.x, md); md = fmaf(A3.y, w3.y, md);
        md = fmaf(A3.z, w3.z, md); md = fmaf(A3.w, w3.w, md);
        ma = fmaf(A4.x, w4.x, ma); ma = fmaf(A4.y, w4.y, ma);
        ma = fmaf(A4.z, w4.z, ma); ma = fmaf(A4.w, w4.w, ma);
        mb = fmaf(A5.x, w5.x, mb); mb = fmaf(A5.y, w5.y, mb);
        mb = fmaf(A5.z, w5.z, mb); mb = fmaf(A5.w, w5.w, mb);
        mc = fmaf(A6.x, w6.x, mc); mc = fmaf(A6.y, w6.y, mc);
        mc = fmaf(A6.z, w6.z, mc); mc = fmaf(A6.w, w6.w, mc);
        md = fmaf(A7.x, w7.x, md); md = fmaf(A7.y, w7.y, md);
        md = fmaf(A7.z, w7.z, md); md = fmaf(A7.w, w7.w, md);
        float m = (ma + mb) + (mc + md);
        float tj = tanhf(m);
        const float4* wp = (const float4*)(sW2 + j * NACT);
        float4 wa = wp[0], wb = wp[1];
        oa.x = fmaf(tj, wa.x, oa.x); oa.y = fmaf(tj, wa.y, oa.y);
        oa.z = fmaf(tj, wa.z, oa.z); oa.w = fmaf(tj, wa.w, oa.w);
        ob.x = fmaf(tj, wb.x, ob.x); ob.y = fmaf(tj, wb.y, ob.y);
        ob.z = fmaf(tj, wb.z, ob.z); ob.w = fmaf(tj, wb.w, ob.w);
    }

    float4* op = (float4*)(out + (size_t)i * NACT);
    op[0] = oa;
    op[1] = ob;
}

extern "C" void kernel_launch(void* const* d_in, const int* in_sizes, int n_in,
                              void* d_out, int out_size, void* d_ws, size_t ws_size,
                              hipStream_t stream) {
    const float* x  = (const float*)d_in[0];
    const int*   ei = (const int*)d_in[1];
    const float* W1 = (const float*)d_in[2];
    const float* b1 = (const float*)d_in[3];
    const float* W2 = (const float*)d_in[4];
    const float* b2 = (const float*)d_in[5];
    float* out = (float*)d_out;

    const int n = in_sizes[0] / NOBS;       // 100000
    const long long e = in_sizes[1] / 2;    // 1600000
    const int B = (n + BNODES - 1) >> BSH;  // 782 buckets

    // ws layout: gcnt int[1024] | arenas B*16KB (entries -> reused as agg)
    //            | dinv f32[n] | y fp16[n*32]   (total ~19.6 MB)
    char* ws = (char*)d_ws;
    int*     gcnt  = (int*)ws;
    char*    arena = ws + 4096;
    float*   dinv  = (float*)(ws + 4096 + (size_t)B * ARENA_B);
    __half2* y2    = (__half2*)(ws + 4096 + (size_t)B * ARENA_B + (size_t)n * 4);

    k_zero<<<4, 256, 0, stream>>>(gcnt, 1024);
    int nsb = (int)((e + SPLIT_E - 1) / SPLIT_E);
    k_split<<<nsb, 256, 0, stream>>>(ei, gcnt, (unsigned int*)arena, e, B);
    k_dinv<<<B, 256, 0, stream>>>((const unsigned int*)arena, gcnt, dinv, n);
    long long ty = (long long)n * (NOBS / 2);
    k_y<<<(int)((ty + 255) / 256), 256, 0, stream>>>(x, dinv, y2, n);
    k_agg<<<B, 512, 0, stream>>>(gcnt, dinv, y2, arena, n);
    k_final<<<(n + 255) / 256, 256, 0, stream>>>(arena, W1, b1, W2, b2, out, n);
}

// Round 6
// 157.197 us; speedup vs baseline: 2.6251x; 2.6251x over previous
//
#include <hip/hip_runtime.h>
#include <hip/hip_fp16.h>
#include <math.h>

// GCNConv QNet: out = tanh( (segsum(x[src]*norm, dst) + selfloop) @ W1 + b1 ) @ W2 + b2
// norm = dinv[src]*dinv[dst], dinv = rsqrt(in_degree + 1).
// Aggregation in 32-dim obs space (W1 applied AFTER segment_sum — linearity).
// R6: multisplit (dst buckets) -> in-bucket LDS counting sort (true CSR, all
// writes coalesced) -> fp16 prescale y=x*dinv -> FUSED wave-per-node
// register-gather + MLP epilogue (no LDS atomics, no agg round-trip).

#define NOBS 32
#define NMID 64
#define NACT 8
#define BSH 7
#define BNODES 128           // nodes per bucket
#define CAP 4096             // max entries per bucket (mean ~2046)
#define ARENA_B 16384        // bytes per bucket arena (= CAP*4)
#define SPLIT_E 4096         // edges per split block

__device__ __forceinline__ bool edges_i64(const int* ei) {
    return (ei[1] | ei[3] | ei[5] | ei[7]) == 0;
}

__global__ void k_zero(int* __restrict__ p, int n) {
    int i = blockIdx.x * blockDim.x + threadIdx.x;
    if (i < n) p[i] = 0;
}

// Multisplit: group 4096 edges by bucket in LDS, flush contiguous runs.
__global__ __launch_bounds__(256) void k_split(
        const int* __restrict__ ei, int* __restrict__ gcnt,
        unsigned int* __restrict__ arena, long long e, int nbuckets) {
    __shared__ int ebuf[SPLIT_E];             // packed entries (16 KB)
    __shared__ unsigned short bbuf[SPLIT_E];  // bucket ids (8 KB)
    __shared__ int sbuf[SPLIT_E];             // bucket-grouped entries (16 KB)
    __shared__ int offs[1024];
    __shared__ int cur[1024];
    __shared__ int tsum[256];
    const int tid = threadIdx.x;

    for (int b = tid; b < 1024; b += 256) cur[b] = 0;  // cur = hist
    __syncthreads();

    const long long base = (long long)blockIdx.x * SPLIT_E;
    const bool i64 = edges_i64(ei);
    const long long* e64 = (const long long*)ei;
    for (int k = tid; k < SPLIT_E; k += 256) {
        long long ge = base + k;
        if (ge < e) {
            int s, d;
            if (i64) { s = (int)e64[ge]; d = (int)e64[e + ge]; }
            else     { s = ei[ge];       d = ei[e + ge]; }
            ebuf[k] = s | ((d & (BNODES - 1)) << 20);
            int b = d >> BSH;
            bbuf[k] = (unsigned short)b;
            atomicAdd(&cur[b], 1);
        } else {
            bbuf[k] = 0xFFFFu;
        }
    }
    __syncthreads();

    // exclusive scan of cur(=hist)[0..1024), 4 bins/thread
    const int t4 = tid * 4;
    int s0 = cur[t4], s1 = cur[t4 + 1], s2 = cur[t4 + 2], s3 = cur[t4 + 3];
    int my = s0 + s1 + s2 + s3;
    tsum[tid] = my;
    __syncthreads();
    for (int off = 1; off < 256; off <<= 1) {
        int t = (tid >= off) ? tsum[tid - off] : 0;
        __syncthreads();
        tsum[tid] += t;
        __syncthreads();
    }
    int ex = tsum[tid] - my;
    offs[t4] = ex;
    offs[t4 + 1] = ex + s0;
    offs[t4 + 2] = ex + s0 + s1;
    offs[t4 + 3] = ex + s0 + s1 + s2;
    __syncthreads();
    for (int b = tid; b < 1024; b += 256) cur[b] = offs[b];  // cursors
    __syncthreads();

    // group into sbuf
    for (int k = tid; k < SPLIT_E; k += 256) {
        int b = bbuf[k];
        if (b != 0xFFFF) {
            int slot = atomicAdd(&cur[b], 1);
            sbuf[slot] = ebuf[k];
        }
    }
    __syncthreads();

    // flush one run per thread (contiguous addresses -> L2 line merge)
    for (int b = tid; b < nbuckets; b += 256) {
        int beg = offs[b];
        int len = cur[b] - beg;
        if (len <= 0) continue;
        int g = atomicAdd(&gcnt[b], len);
        if (g >= CAP) continue;
        if (g + len > CAP) len = CAP - g;
        unsigned int* dst = arena + (size_t)b * CAP + g;
        for (int j = 0; j < len; ++j) dst[j] = (unsigned int)sbuf[beg + j];
    }
}

// In-bucket counting sort by dlocal -> node-contiguous runs (coalesced write-
// back). Also emits pk[node] = (global beg)|(cnt<<22) and dinv.
__global__ __launch_bounds__(256) void k_sort(
        const int* __restrict__ gcnt, unsigned int* __restrict__ arena,
        unsigned int* __restrict__ pk, float* __restrict__ dinv, int n) {
    __shared__ unsigned int sbuf[CAP];   // 16 KB
    __shared__ unsigned int obuf[CAP];   // 16 KB
    __shared__ int hist[BNODES];
    __shared__ int offs[BNODES];
    __shared__ int cur[BNODES];
    const int b = blockIdx.x, tid = threadIdx.x;
    const int count = min(gcnt[b], CAP);
    unsigned int* ent = arena + (size_t)b * CAP;

    if (tid < BNODES) hist[tid] = 0;
    __syncthreads();
    for (int p = tid; p < count; p += 256) {
        unsigned int v = ent[p];
        sbuf[p] = v;
        atomicAdd(&hist[v >> 20], 1);
    }
    __syncthreads();
    if (tid < BNODES) offs[tid] = hist[tid];
    __syncthreads();
    for (int off = 1; off < BNODES; off <<= 1) {
        int t = 0;
        if (tid < BNODES && tid >= off) t = offs[tid - off];
        __syncthreads();
        if (tid < BNODES) offs[tid] += t;
        __syncthreads();
    }
    if (tid < BNODES) {
        int ex = offs[tid] - hist[tid];   // exclusive
        cur[tid] = ex;
        int node = b * BNODES + tid;
        if (node < n) {
            pk[node] = (unsigned int)(b * CAP + ex) | ((unsigned int)hist[tid] << 22);
            dinv[node] = rsqrtf((float)(hist[tid] + 1));
        }
    }
    __syncthreads();
    for (int p = tid; p < count; p += 256) {
        unsigned int v = sbuf[p];
        int pos = atomicAdd(&cur[v >> 20], 1);
        obuf[pos] = v;
    }
    __syncthreads();
    for (int p = tid; p < count; p += 256) ent[p] = obuf[p];
}

// Prescale: y[i][c] = x[i][c] * dinv[i], fp16. 2 channels per thread.
__global__ void k_y(const float* __restrict__ x, const float* __restrict__ dinv,
                    __half2* __restrict__ y2, int n) {
    long long t = (long long)blockIdx.x * blockDim.x + threadIdx.x;  // over n*16
    if (t >= (long long)n * (NOBS / 2)) return;
    int i = (int)(t >> 4);
    float di = dinv[i];
    float2 v = ((const float2*)x)[t];
    y2[t] = __floats2half2_rn(v.x * di, v.y * di);
}

// Fused: wave-per-node register gather + MLP epilogue.
// Gather: 4 lane-groups x 16 lanes; each group walks every 4th entry with a
// 2-deep unroll (8 independent 64B row gathers in flight per wave), float2
// accumulate in registers, shfl-reduce across groups.
// Epilogue: lane j computes m_j (W1 row-major in LDS -> conflict-free),
// tanh, then 8-output shfl butterfly reduce.
__global__ __launch_bounds__(256) void k_fused(
        const unsigned int* __restrict__ arena, const unsigned int* __restrict__ pk,
        const float* __restrict__ dinv, const __half2* __restrict__ y2,
        const float* __restrict__ W1, const float* __restrict__ b1,
        const float* __restrict__ W2, const float* __restrict__ b2,
        float* __restrict__ out, int n) {
    __shared__ float sW1[NOBS * NMID];   // W1[c][j] at c*64+j (input layout)
    __shared__ float sW2T[NACT * NMID];  // W2T[k][j] at k*64+j
    __shared__ float sb1[NMID];
    __shared__ float sb2[NACT];
    __shared__ float sA[4][NOBS];
    const int tid = threadIdx.x;
    for (int t = tid; t < NOBS * NMID; t += 256) sW1[t] = W1[t];
    for (int t = tid; t < NMID * NACT; t += 256) {
        int j = t >> 3, k = t & 7;       // W2[j][k]
        sW2T[k * NMID + j] = W2[t];
    }
    if (tid < NMID) sb1[tid] = b1[tid];
    if (tid < NACT) sb2[tid] = b2[tid];

    const int wid = tid >> 6;
    const int lane = tid & 63;
    const int g = lane >> 4, l = lane & 15;
    const int node = blockIdx.x * 4 + wid;

    float2 acc = make_float2(0.f, 0.f);
    float din = 0.f;
    if (node < n) {
        din = dinv[node];
        unsigned int p = pk[node];
        int beg = (int)(p & 0x3FFFFF);
        int cnt = (int)(p >> 22);
        if (g == 0) {
            float2 self = __half22float2(y2[(size_t)node * 16 + l]);
            acc.x = self.x; acc.y = self.y;
        }
        const unsigned int* ent = arena + beg;
        int i = g;
        for (; i + 4 < cnt; i += 8) {
            unsigned int e0 = ent[i], e1 = ent[i + 4];
            float2 v0 = __half22float2(y2[(size_t)(e0 & 0xFFFFF) * 16 + l]);
            float2 v1 = __half22float2(y2[(size_t)(e1 & 0xFFFFF) * 16 + l]);
            acc.x += v0.x + v1.x;
            acc.y += v0.y + v1.y;
        }
        if (i < cnt) {
            unsigned int e0 = ent[i];
            float2 v0 = __half22float2(y2[(size_t)(e0 & 0xFFFFF) * 16 + l]);
            acc.x += v0.x;
            acc.y += v0.y;
        }
    }
    acc.x += __shfl_xor(acc.x, 16);
    acc.y += __shfl_xor(acc.y, 16);
    acc.x += __shfl_xor(acc.x, 32);
    acc.y += __shfl_xor(acc.y, 32);
    if (node < n && g == 0) {
        sA[wid][2 * l] = acc.x * din;
        sA[wid][2 * l + 1] = acc.y * din;
    }
    __syncthreads();

    if (node >= n) return;
    const int j = lane;                  // 0..63 = NMID
    float m = sb1[j];
    const float* a = sA[wid];
#pragma unroll 8
    for (int c = 0; c < NOBS; ++c) m = fmaf(a[c], sW1[c * NMID + j], m);
    float tj = tanhf(m);
    float o0 = tj * sW2T[0 * NMID + j], o1 = tj * sW2T[1 * NMID + j];
    float o2 = tj * sW2T[2 * NMID + j], o3 = tj * sW2T[3 * NMID + j];
    float o4 = tj * sW2T[4 * NMID + j], o5 = tj * sW2T[5 * NMID + j];
    float o6 = tj * sW2T[6 * NMID + j], o7 = tj * sW2T[7 * NMID + j];
    for (int off = 1; off < 64; off <<= 1) {
        o0 += __shfl_xor(o0, off); o1 += __shfl_xor(o1, off);
        o2 += __shfl_xor(o2, off); o3 += __shfl_xor(o3, off);
        o4 += __shfl_xor(o4, off); o5 += __shfl_xor(o5, off);
        o6 += __shfl_xor(o6, off); o7 += __shfl_xor(o7, off);
    }
    if (lane < 8) {
        float v = lane == 0 ? o0 : lane == 1 ? o1 : lane == 2 ? o2 : lane == 3 ? o3
                : lane == 4 ? o4 : lane == 5 ? o5 : lane == 6 ? o6 : o7;
        out[(size_t)node * NACT + lane] = v + sb2[lane];
    }
}

extern "C" void kernel_launch(void* const* d_in, const int* in_sizes, int n_in,
                              void* d_out, int out_size, void* d_ws, size_t ws_size,
                              hipStream_t stream) {
    const float* x  = (const float*)d_in[0];
    const int*   ei = (const int*)d_in[1];
    const float* W1 = (const float*)d_in[2];
    const float* b1 = (const float*)d_in[3];
    const float* W2 = (const float*)d_in[4];
    const float* b2 = (const float*)d_in[5];
    float* out = (float*)d_out;

    const int n = in_sizes[0] / NOBS;       // 100000
    const long long e = in_sizes[1] / 2;    // 1600000
    const int B = (n + BNODES - 1) >> BSH;  // 782 buckets

    // ws layout (20.0 MB):
    //   gcnt int[1024]        @ 0
    //   arena uint[B*CAP]     @ 4096          (12,812,288 B)
    //   pk   uint[n]          @ 12,816,384    (400,000 B)
    //   dinv f32[n]           @ 13,216,384    (400,000 B)
    //   y2   half2[n*16]      @ 13,616,384    (6,400,000 B)
    char* ws = (char*)d_ws;
    int*          gcnt  = (int*)ws;
    unsigned int* arena = (unsigned int*)(ws + 4096);
    unsigned int* pk    = (unsigned int*)(ws + 4096 + (size_t)B * ARENA_B);
    float*        dinv  = (float*)(ws + 4096 + (size_t)B * ARENA_B + (size_t)n * 4);
    __half2*      y2    = (__half2*)(ws + 4096 + (size_t)B * ARENA_B + (size_t)n * 8);

    k_zero<<<4, 256, 0, stream>>>(gcnt, 1024);
    int nsb = (int)((e + SPLIT_E - 1) / SPLIT_E);
    k_split<<<nsb, 256, 0, stream>>>(ei, gcnt, arena, e, B);
    k_sort<<<B, 256, 0, stream>>>(gcnt, arena, pk, dinv, n);
    long long ty = (long long)n * (NOBS / 2);
    k_y<<<(int)((ty + 255) / 256), 256, 0, stream>>>(x, dinv, y2, n);
    k_fused<<<(n + 3) / 4, 256, 0, stream>>>(arena, pk, dinv, y2, W1, b1, W2, b2, out, n);
}

// Round 7
// 121.976 us; speedup vs baseline: 3.3832x; 1.2888x over previous
//
#include <hip/hip_runtime.h>
#include <hip/hip_fp16.h>
#include <math.h>

// GCNConv QNet: out = tanh( (segsum(x[src]*norm, dst) + selfloop) @ W1 + b1 ) @ W2 + b2
// norm = dinv[src]*dinv[dst], dinv = rsqrt(in_degree + 1).
// Aggregation in 32-dim obs space (W1 applied AFTER segment_sum — linearity).
// R7: multisplit -> in-bucket counting sort (CSR, fused fp16 y=x*dinv write)
// -> fused wave-per-node register gather (8 lanes x 8B, 16 loads in flight)
// + MLP epilogue with LDS-t + pad-9 W2 (no 48-shfl butterfly).

#define NOBS 32
#define NMID 64
#define NACT 8
#define BSH 7
#define BNODES 128           // nodes per bucket
#define CAP 4096             // max entries per bucket (mean ~2046)
#define ARENA_B 16384        // bytes per bucket arena (= CAP*4)
#define SPLIT_E 4096         // edges per split block

__device__ __forceinline__ bool edges_i64(const int* ei) {
    return (ei[1] | ei[3] | ei[5] | ei[7]) == 0;
}

// Multisplit: group 4096 edges by bucket in LDS, flush contiguous runs.
__global__ __launch_bounds__(256) void k_split(
        const int* __restrict__ ei, int* __restrict__ gcnt,
        unsigned int* __restrict__ arena, long long e, int nbuckets) {
    __shared__ int ebuf[SPLIT_E];             // packed entries (16 KB)
    __shared__ unsigned short bbuf[SPLIT_E];  // bucket ids (8 KB)
    __shared__ int sbuf[SPLIT_E];             // bucket-grouped entries (16 KB)
    __shared__ int offs[1024];
    __shared__ int cur[1024];
    __shared__ int tsum[256];
    const int tid = threadIdx.x;

    for (int b = tid; b < 1024; b += 256) cur[b] = 0;  // cur = hist
    __syncthreads();

    const long long base = (long long)blockIdx.x * SPLIT_E;
    const bool i64 = edges_i64(ei);
    const long long* e64 = (const long long*)ei;
    for (int k = tid; k < SPLIT_E; k += 256) {
        long long ge = base + k;
        if (ge < e) {
            int s, d;
            if (i64) { s = (int)e64[ge]; d = (int)e64[e + ge]; }
            else     { s = ei[ge];       d = ei[e + ge]; }
            ebuf[k] = s | ((d & (BNODES - 1)) << 20);
            int b = d >> BSH;
            bbuf[k] = (unsigned short)b;
            atomicAdd(&cur[b], 1);
        } else {
            bbuf[k] = 0xFFFFu;
        }
    }
    __syncthreads();

    // exclusive scan of cur(=hist)[0..1024), 4 bins/thread
    const int t4 = tid * 4;
    int s0 = cur[t4], s1 = cur[t4 + 1], s2 = cur[t4 + 2], s3 = cur[t4 + 3];
    int my = s0 + s1 + s2 + s3;
    tsum[tid] = my;
    __syncthreads();
    for (int off = 1; off < 256; off <<= 1) {
        int t = (tid >= off) ? tsum[tid - off] : 0;
        __syncthreads();
        tsum[tid] += t;
        __syncthreads();
    }
    int ex = tsum[tid] - my;
    offs[t4] = ex;
    offs[t4 + 1] = ex + s0;
    offs[t4 + 2] = ex + s0 + s1;
    offs[t4 + 3] = ex + s0 + s1 + s2;
    __syncthreads();
    for (int b = tid; b < 1024; b += 256) cur[b] = offs[b];  // cursors
    __syncthreads();

    // group into sbuf
    for (int k = tid; k < SPLIT_E; k += 256) {
        int b = bbuf[k];
        if (b != 0xFFFF) {
            int slot = atomicAdd(&cur[b], 1);
            sbuf[slot] = ebuf[k];
        }
    }
    __syncthreads();

    // flush one run per thread (contiguous addresses -> L2 line merge)
    for (int b = tid; b < nbuckets; b += 256) {
        int beg = offs[b];
        int len = cur[b] - beg;
        if (len <= 0) continue;
        int g = atomicAdd(&gcnt[b], len);
        if (g >= CAP) continue;
        if (g + len > CAP) len = CAP - g;
        unsigned int* dst = arena + (size_t)b * CAP + g;
        for (int j = 0; j < len; ++j) dst[j] = (unsigned int)sbuf[beg + j];
    }
}

// In-bucket counting sort by dlocal -> node-contiguous runs. Emits
// pk[node] = beg|(cnt<<22), dinv, and the fp16 prescaled y = x*dinv rows
// for this bucket's 128 nodes (fused former k_y).
__global__ __launch_bounds__(256) void k_sort(
        const int* __restrict__ gcnt, unsigned int* __restrict__ arena,
        const float* __restrict__ x, unsigned int* __restrict__ pk,
        float* __restrict__ dinv, __half2* __restrict__ y2, int n) {
    __shared__ unsigned int sbuf[CAP];   // 16 KB
    __shared__ unsigned int obuf[CAP];   // 16 KB
    __shared__ int hist[BNODES];
    __shared__ int offs[BNODES];
    __shared__ int cur[BNODES];
    __shared__ float rinv[BNODES];
    const int b = blockIdx.x, tid = threadIdx.x;
    const int count = min(gcnt[b], CAP);
    unsigned int* ent = arena + (size_t)b * CAP;

    if (tid < BNODES) hist[tid] = 0;
    __syncthreads();
    for (int p = tid; p < count; p += 256) {
        unsigned int v = ent[p];
        sbuf[p] = v;
        atomicAdd(&hist[v >> 20], 1);
    }
    __syncthreads();
    if (tid < BNODES) offs[tid] = hist[tid];
    __syncthreads();
    for (int off = 1; off < BNODES; off <<= 1) {
        int t = 0;
        if (tid < BNODES && tid >= off) t = offs[tid - off];
        __syncthreads();
        if (tid < BNODES) offs[tid] += t;
        __syncthreads();
    }
    if (tid < BNODES) {
        int ex = offs[tid] - hist[tid];   // exclusive
        cur[tid] = ex;
        float r = rsqrtf((float)(hist[tid] + 1));
        rinv[tid] = r;
        int node = b * BNODES + tid;
        if (node < n) {
            pk[node] = (unsigned int)(b * CAP + ex) | ((unsigned int)hist[tid] << 22);
            dinv[node] = r;
        }
    }
    __syncthreads();
    for (int p = tid; p < count; p += 256) {
        unsigned int v = sbuf[p];
        int pos = atomicAdd(&cur[v >> 20], 1);
        obuf[pos] = v;
    }
    // y write overlaps the sort scatter (independent of obuf)
    for (int idx = tid; idx < BNODES * 16; idx += 256) {
        int node = b * BNODES + (idx >> 4);
        if (node >= n) break;
        float r = rinv[idx >> 4];
        float2 v = ((const float2*)x)[(size_t)node * 16 + (idx & 15)];
        y2[(size_t)node * 16 + (idx & 15)] = __floats2half2_rn(v.x * r, v.y * r);
    }
    __syncthreads();
    for (int p = tid; p < count; p += 256) ent[p] = obuf[p];
}

// Fused: wave-per-node register gather + MLP epilogue.
// Gather: 8 lane-groups x 8 lanes; lane covers 4 channels (8B uint2 of y2);
// unroll 2 -> 16 independent 64B row gathers in flight per wave.
// Epilogue: lane j computes m_j; tanh -> per-wave LDS row; all lanes do
// 8-FMA partial dot over pad-9 W2 + 3-step shfl reduce.
__global__ __launch_bounds__(256) void k_fused(
        const unsigned int* __restrict__ arena, const unsigned int* __restrict__ pk,
        const float* __restrict__ dinv, const __half2* __restrict__ y2,
        const float* __restrict__ W1, const float* __restrict__ b1,
        const float* __restrict__ W2, const float* __restrict__ b2,
        float* __restrict__ out, int n) {
    __shared__ float sW1[NOBS * NMID];   // W1[c][j] at c*64+j (input layout)
    __shared__ float sW2p[NMID * 9];     // W2[j][k] at j*9+k (pad-9: 2-way max)
    __shared__ float sb1[NMID];
    __shared__ float sb2[NACT];
    __shared__ float sA[4][NOBS];        // per-wave agg row
    __shared__ float sT[4][NMID];        // per-wave tanh row
    const int tid = threadIdx.x;
    for (int t = tid; t < NOBS * NMID; t += 256) sW1[t] = W1[t];
    for (int t = tid; t < NMID * NACT; t += 256) sW2p[(t >> 3) * 9 + (t & 7)] = W2[t];
    if (tid < NMID) sb1[tid] = b1[tid];
    if (tid < NACT) sb2[tid] = b2[tid];

    const int wid = tid >> 6;
    const int lane = tid & 63;
    const int g = lane >> 3, l = lane & 7;   // 8 groups x 8 lanes
    const int node = blockIdx.x * 4 + wid;
    const bool valid = node < n;

    float4 acc = make_float4(0.f, 0.f, 0.f, 0.f);
    float din = 0.f;
    int beg = 0, cnt = 0;
    if (valid) {
        din = dinv[node];
        unsigned int p = pk[node];
        beg = (int)(p & 0x3FFFFF);
        cnt = (int)(p >> 22);
    }
    if (valid && g == 0) {  // self-loop row
        uint2 sv = ((const uint2*)(y2 + (size_t)node * 16))[l];
        float2 f0 = __half22float2(*reinterpret_cast<const __half2*>(&sv.x));
        float2 f1 = __half22float2(*reinterpret_cast<const __half2*>(&sv.y));
        acc.x = f0.x; acc.y = f0.y; acc.z = f1.x; acc.w = f1.y;
    }
    const unsigned int* ent = arena + beg;
    int i = g;
    for (; i + 8 < cnt; i += 16) {
        unsigned int e0 = ent[i], e1 = ent[i + 8];
        uint2 v0 = ((const uint2*)(y2 + (size_t)(e0 & 0xFFFFF) * 16))[l];
        uint2 v1 = ((const uint2*)(y2 + (size_t)(e1 & 0xFFFFF) * 16))[l];
        float2 a0 = __half22float2(*reinterpret_cast<const __half2*>(&v0.x));
        float2 a1 = __half22float2(*reinterpret_cast<const __half2*>(&v0.y));
        float2 b0 = __half22float2(*reinterpret_cast<const __half2*>(&v1.x));
        float2 b1f = __half22float2(*reinterpret_cast<const __half2*>(&v1.y));
        acc.x += a0.x + b0.x; acc.y += a0.y + b0.y;
        acc.z += a1.x + b1f.x; acc.w += a1.y + b1f.y;
    }
    if (i < cnt) {
        unsigned int e0 = ent[i];
        uint2 v0 = ((const uint2*)(y2 + (size_t)(e0 & 0xFFFFF) * 16))[l];
        float2 a0 = __half22float2(*reinterpret_cast<const __half2*>(&v0.x));
        float2 a1 = __half22float2(*reinterpret_cast<const __half2*>(&v0.y));
        acc.x += a0.x; acc.y += a0.y; acc.z += a1.x; acc.w += a1.y;
    }
    // reduce across the 8 groups (lane bits 3..5)
    acc.x += __shfl_xor(acc.x, 8);  acc.y += __shfl_xor(acc.y, 8);
    acc.z += __shfl_xor(acc.z, 8);  acc.w += __shfl_xor(acc.w, 8);
    acc.x += __shfl_xor(acc.x, 16); acc.y += __shfl_xor(acc.y, 16);
    acc.z += __shfl_xor(acc.z, 16); acc.w += __shfl_xor(acc.w, 16);
    acc.x += __shfl_xor(acc.x, 32); acc.y += __shfl_xor(acc.y, 32);
    acc.z += __shfl_xor(acc.z, 32); acc.w += __shfl_xor(acc.w, 32);
    if (valid && g == 0) {
        ((float4*)sA[wid])[l] = make_float4(acc.x * din, acc.y * din,
                                            acc.z * din, acc.w * din);
    }
    __syncthreads();  // also covers the weight staging at the top

    // m_j per lane, tanh into sT
    const int j = lane;
    float m = sb1[j];
    const float* a = sA[wid];
#pragma unroll 8
    for (int c = 0; c < NOBS; ++c) m = fmaf(a[c], sW1[c * NMID + j], m);
    sT[wid][j] = tanhf(m);
    __syncthreads();

    // o_k: lane = jg*8 + k; 8-FMA partial over jj, then reduce over jg
    const int k = lane & 7, jg = lane >> 3;
    float o = 0.f;
#pragma unroll
    for (int jj = 0; jj < 8; ++jj) {
        int jr = jg * 8 + jj;
        o = fmaf(sT[wid][jr], sW2p[jr * 9 + k], o);
    }
    o += __shfl_xor(o, 8);
    o += __shfl_xor(o, 16);
    o += __shfl_xor(o, 32);
    if (valid && jg == 0)
        out[(size_t)node * NACT + k] = o + sb2[k];
}

extern "C" void kernel_launch(void* const* d_in, const int* in_sizes, int n_in,
                              void* d_out, int out_size, void* d_ws, size_t ws_size,
                              hipStream_t stream) {
    const float* x  = (const float*)d_in[0];
    const int*   ei = (const int*)d_in[1];
    const float* W1 = (const float*)d_in[2];
    const float* b1 = (const float*)d_in[3];
    const float* W2 = (const float*)d_in[4];
    const float* b2 = (const float*)d_in[5];
    float* out = (float*)d_out;

    const int n = in_sizes[0] / NOBS;       // 100000
    const long long e = in_sizes[1] / 2;    // 1600000
    const int B = (n + BNODES - 1) >> BSH;  // 782 buckets

    // ws layout (20.0 MB):
    //   gcnt int[1024]        @ 0
    //   arena uint[B*CAP]     @ 4096
    //   pk   uint[n]          @ 4096 + B*16384
    //   dinv f32[n]           @ ... + n*4
    //   y2   half2[n*16]      @ ... + n*8
    char* ws = (char*)d_ws;
    int*          gcnt  = (int*)ws;
    unsigned int* arena = (unsigned int*)(ws + 4096);
    unsigned int* pk    = (unsigned int*)(ws + 4096 + (size_t)B * ARENA_B);
    float*        dinv  = (float*)(ws + 4096 + (size_t)B * ARENA_B + (size_t)n * 4);
    __half2*      y2    = (__half2*)(ws + 4096 + (size_t)B * ARENA_B + (size_t)n * 8);

    hipMemsetAsync(gcnt, 0, 4096, stream);
    int nsb = (int)((e + SPLIT_E - 1) / SPLIT_E);
    k_split<<<nsb, 256, 0, stream>>>(ei, gcnt, arena, e, B);
    k_sort<<<B, 256, 0, stream>>>(gcnt, arena, x, pk, dinv, y2, n);
    k_fused<<<(n + 3) / 4, 256, 0, stream>>>(arena, pk, dinv, y2, W1, b1, W2, b2, out, n);
}

// Round 9
// 104.446 us; speedup vs baseline: 3.9510x; 1.1678x over previous
//
#include <hip/hip_runtime.h>
#include <hip/hip_fp16.h>
#include <math.h>

// GCNConv QNet: out = tanh( (segsum(x[src]*norm, dst) + selfloop) @ W1 + b1 ) @ W2 + b2
// norm = dinv[src]*dinv[dst], dinv = rsqrt(in_degree + 1).
// Aggregation in 32-dim obs space (W1 applied AFTER segment_sum — linearity).
// R9: R8 structure with the two __syncthreads() per node-iteration RESTORED
// (R8's barrier-free same-wave LDS handoff raced under compiler reordering).
// Kept from R8: NPW=4 (weight staging amortized 4x), paired edge loads,
// fast branch-free tanh.

#define NOBS 32
#define NMID 64
#define NACT 8
#define BSH 7
#define BNODES 128           // nodes per bucket
#define CAP 4096             // max entries per bucket (mean ~2046)
#define ARENA_B 16384        // bytes per bucket arena (= CAP*4)
#define SPLIT_E 4096         // edges per split block
#define NPW 4                // nodes per wave in k_fused

__device__ __forceinline__ bool edges_i64(const int* ei) {
    return (ei[1] | ei[3] | ei[5] | ei[7]) == 0;
}

// tanh(x) = 1 - 2/(1+e^{2x}); exact at +-inf, ~1e-5 rel err, branch-free.
__device__ __forceinline__ float fast_tanh(float x) {
    float t = __expf(2.f * x);
    return 1.f - 2.f * __builtin_amdgcn_rcpf(1.f + t);
}

// Multisplit: group 4096 edges by bucket in LDS, flush contiguous runs.
__global__ __launch_bounds__(256) void k_split(
        const int* __restrict__ ei, int* __restrict__ gcnt,
        unsigned int* __restrict__ arena, long long e, int nbuckets) {
    __shared__ int ebuf[SPLIT_E];             // packed entries (16 KB)
    __shared__ unsigned short bbuf[SPLIT_E];  // bucket ids (8 KB)
    __shared__ int sbuf[SPLIT_E];             // bucket-grouped entries (16 KB)
    __shared__ int offs[1024];
    __shared__ int cur[1024];
    __shared__ int tsum[256];
    const int tid = threadIdx.x;

    for (int b = tid; b < 1024; b += 256) cur[b] = 0;  // cur = hist
    __syncthreads();

    const long long base = (long long)blockIdx.x * SPLIT_E;
    const bool i64 = edges_i64(ei);
    const long long* e64 = (const long long*)ei;
    for (int k = tid * 2; k < SPLIT_E; k += 512) {
        long long ge = base + k;
        if (ge + 1 < e) {  // paired 16B/8B loads
            int s0, d0, s1, d1;
            if (i64) {
                ulonglong2 sp = *(const ulonglong2*)(e64 + ge);
                ulonglong2 dp = *(const ulonglong2*)(e64 + e + ge);
                s0 = (int)sp.x; s1 = (int)sp.y; d0 = (int)dp.x; d1 = (int)dp.y;
            } else {
                int2 sp = *(const int2*)(ei + ge);
                int2 dp = *(const int2*)(ei + e + ge);
                s0 = sp.x; s1 = sp.y; d0 = dp.x; d1 = dp.y;
            }
            ebuf[k] = s0 | ((d0 & (BNODES - 1)) << 20);
            bbuf[k] = (unsigned short)(d0 >> BSH);
            atomicAdd(&cur[d0 >> BSH], 1);
            ebuf[k + 1] = s1 | ((d1 & (BNODES - 1)) << 20);
            bbuf[k + 1] = (unsigned short)(d1 >> BSH);
            atomicAdd(&cur[d1 >> BSH], 1);
        } else if (ge < e) {
            int s, d;
            if (i64) { s = (int)e64[ge]; d = (int)e64[e + ge]; }
            else     { s = ei[ge];       d = ei[e + ge]; }
            ebuf[k] = s | ((d & (BNODES - 1)) << 20);
            bbuf[k] = (unsigned short)(d >> BSH);
            atomicAdd(&cur[d >> BSH], 1);
            bbuf[k + 1] = 0xFFFFu;
        } else {
            bbuf[k] = 0xFFFFu;
            bbuf[k + 1] = 0xFFFFu;
        }
    }
    __syncthreads();

    // exclusive scan of cur(=hist)[0..1024), 4 bins/thread
    const int t4 = tid * 4;
    int s0 = cur[t4], s1 = cur[t4 + 1], s2 = cur[t4 + 2], s3 = cur[t4 + 3];
    int my = s0 + s1 + s2 + s3;
    tsum[tid] = my;
    __syncthreads();
    for (int off = 1; off < 256; off <<= 1) {
        int t = (tid >= off) ? tsum[tid - off] : 0;
        __syncthreads();
        tsum[tid] += t;
        __syncthreads();
    }
    int ex = tsum[tid] - my;
    offs[t4] = ex;
    offs[t4 + 1] = ex + s0;
    offs[t4 + 2] = ex + s0 + s1;
    offs[t4 + 3] = ex + s0 + s1 + s2;
    __syncthreads();
    for (int b = tid; b < 1024; b += 256) cur[b] = offs[b];  // cursors
    __syncthreads();

    // group into sbuf
    for (int k = tid; k < SPLIT_E; k += 256) {
        int b = bbuf[k];
        if (b != 0xFFFF) {
            int slot = atomicAdd(&cur[b], 1);
            sbuf[slot] = ebuf[k];
        }
    }
    __syncthreads();

    // flush one run per thread (contiguous addresses -> L2 line merge)
    for (int b = tid; b < nbuckets; b += 256) {
        int beg = offs[b];
        int len = cur[b] - beg;
        if (len <= 0) continue;
        int g = atomicAdd(&gcnt[b], len);
        if (g >= CAP) continue;
        if (g + len > CAP) len = CAP - g;
        unsigned int* dst = arena + (size_t)b * CAP + g;
        for (int j = 0; j < len; ++j) dst[j] = (unsigned int)sbuf[beg + j];
    }
}

// In-bucket counting sort by dlocal -> node-contiguous runs. Emits
// pk[node] = beg|(cnt<<22), dinv, and fp16 prescaled y = x*dinv rows.
__global__ __launch_bounds__(256) void k_sort(
        const int* __restrict__ gcnt, unsigned int* __restrict__ arena,
        const float* __restrict__ x, unsigned int* __restrict__ pk,
        float* __restrict__ dinv, __half2* __restrict__ y2, int n) {
    __shared__ unsigned int sbuf[CAP];   // 16 KB
    __shared__ unsigned int obuf[CAP];   // 16 KB
    __shared__ int hist[BNODES];
    __shared__ int offs[BNODES];
    __shared__ int cur[BNODES];
    __shared__ float rinv[BNODES];
    const int b = blockIdx.x, tid = threadIdx.x;
    const int count = min(gcnt[b], CAP);
    unsigned int* ent = arena + (size_t)b * CAP;

    if (tid < BNODES) hist[tid] = 0;
    __syncthreads();
    for (int p = tid; p < count; p += 256) {
        unsigned int v = ent[p];
        sbuf[p] = v;
        atomicAdd(&hist[v >> 20], 1);
    }
    __syncthreads();
    if (tid < BNODES) offs[tid] = hist[tid];
    __syncthreads();
    for (int off = 1; off < BNODES; off <<= 1) {
        int t = 0;
        if (tid < BNODES && tid >= off) t = offs[tid - off];
        __syncthreads();
        if (tid < BNODES) offs[tid] += t;
        __syncthreads();
    }
    if (tid < BNODES) {
        int ex = offs[tid] - hist[tid];   // exclusive
        cur[tid] = ex;
        float r = rsqrtf((float)(hist[tid] + 1));
        rinv[tid] = r;
        int node = b * BNODES + tid;
        if (node < n) {
            pk[node] = (unsigned int)(b * CAP + ex) | ((unsigned int)hist[tid] << 22);
            dinv[node] = r;
        }
    }
    __syncthreads();
    for (int p = tid; p < count; p += 256) {
        unsigned int v = sbuf[p];
        int pos = atomicAdd(&cur[v >> 20], 1);
        obuf[pos] = v;
    }
    // y write overlaps the sort scatter (independent of obuf)
    for (int idx = tid; idx < BNODES * 16; idx += 256) {
        int node = b * BNODES + (idx >> 4);
        if (node >= n) break;
        float r = rinv[idx >> 4];
        float2 v = ((const float2*)x)[(size_t)node * 16 + (idx & 15)];
        y2[(size_t)node * 16 + (idx & 15)] = __floats2half2_rn(v.x * r, v.y * r);
    }
    __syncthreads();
    for (int p = tid; p < count; p += 256) ent[p] = obuf[p];
}

// Fused: wave handles NPW nodes; per node: 8 lane-groups x 8 lanes register
// gather (16 row-loads in flight), shfl reduce, LDS handoff WITH barriers
// (uniform loop -> barrier-legal), MLP epilogue with fast tanh + pad-9 W2.
__global__ __launch_bounds__(256) void k_fused(
        const unsigned int* __restrict__ arena, const unsigned int* __restrict__ pk,
        const float* __restrict__ dinv, const __half2* __restrict__ y2,
        const float* __restrict__ W1, const float* __restrict__ b1,
        const float* __restrict__ W2, const float* __restrict__ b2,
        float* __restrict__ out, int n) {
    __shared__ float sW1[NOBS * NMID];   // W1[c][j] at c*64+j (input layout)
    __shared__ float sW2p[NMID * 9];     // W2[j][k] at j*9+k (pad-9)
    __shared__ float sb1[NMID];
    __shared__ float sb2[NACT];
    __shared__ float sA[4][NOBS];        // per-wave agg row
    __shared__ float sT[4][NMID];        // per-wave tanh row
    const int tid = threadIdx.x;
    for (int t = tid; t < NOBS * NMID; t += 256) sW1[t] = W1[t];
    for (int t = tid; t < NMID * NACT; t += 256) sW2p[(t >> 3) * 9 + (t & 7)] = W2[t];
    if (tid < NMID) sb1[tid] = b1[tid];
    if (tid < NACT) sb2[tid] = b2[tid];
    __syncthreads();

    const int wid = tid >> 6;
    const int lane = tid & 63;
    const int g = lane >> 3, l = lane & 7;   // 8 groups x 8 lanes
    const int k = lane & 7, jg = lane >> 3;  // epilogue mapping
    const int nodeBase = blockIdx.x * (4 * NPW) + wid * NPW;

    for (int nn = 0; nn < NPW; ++nn) {
        const int node = nodeBase + nn;
        const bool valid = node < n;

        float4 acc = make_float4(0.f, 0.f, 0.f, 0.f);
        float din = 0.f;
        int beg = 0, cnt = 0;
        if (valid) {
            din = dinv[node];
            unsigned int p = pk[node];
            beg = (int)(p & 0x3FFFFF);
            cnt = (int)(p >> 22);
        }
        if (valid && g == 0) {  // self-loop row
            uint2 sv = ((const uint2*)(y2 + (size_t)node * 16))[l];
            float2 f0 = __half22float2(*reinterpret_cast<const __half2*>(&sv.x));
            float2 f1 = __half22float2(*reinterpret_cast<const __half2*>(&sv.y));
            acc.x = f0.x; acc.y = f0.y; acc.z = f1.x; acc.w = f1.y;
        }
        const unsigned int* ent = arena + beg;
        int i = g;
        for (; i + 8 < cnt; i += 16) {
            unsigned int e0 = ent[i], e1 = ent[i + 8];
            uint2 v0 = ((const uint2*)(y2 + (size_t)(e0 & 0xFFFFF) * 16))[l];
            uint2 v1 = ((const uint2*)(y2 + (size_t)(e1 & 0xFFFFF) * 16))[l];
            float2 a0 = __half22float2(*reinterpret_cast<const __half2*>(&v0.x));
            float2 a1 = __half22float2(*reinterpret_cast<const __half2*>(&v0.y));
            float2 b0 = __half22float2(*reinterpret_cast<const __half2*>(&v1.x));
            float2 b1f = __half22float2(*reinterpret_cast<const __half2*>(&v1.y));
            acc.x += a0.x + b0.x; acc.y += a0.y + b0.y;
            acc.z += a1.x + b1f.x; acc.w += a1.y + b1f.y;
        }
        if (i < cnt) {
            unsigned int e0 = ent[i];
            uint2 v0 = ((const uint2*)(y2 + (size_t)(e0 & 0xFFFFF) * 16))[l];
            float2 a0 = __half22float2(*reinterpret_cast<const __half2*>(&v0.x));
            float2 a1 = __half22float2(*reinterpret_cast<const __half2*>(&v0.y));
            acc.x += a0.x; acc.y += a0.y; acc.z += a1.x; acc.w += a1.y;
        }
        // reduce across the 8 groups (lane bits 3..5)
        acc.x += __shfl_xor(acc.x, 8);  acc.y += __shfl_xor(acc.y, 8);
        acc.z += __shfl_xor(acc.z, 8);  acc.w += __shfl_xor(acc.w, 8);
        acc.x += __shfl_xor(acc.x, 16); acc.y += __shfl_xor(acc.y, 16);
        acc.z += __shfl_xor(acc.z, 16); acc.w += __shfl_xor(acc.w, 16);
        acc.x += __shfl_xor(acc.x, 32); acc.y += __shfl_xor(acc.y, 32);
        acc.z += __shfl_xor(acc.z, 32); acc.w += __shfl_xor(acc.w, 32);
        if (valid && g == 0) {
            ((float4*)sA[wid])[l] = make_float4(acc.x * din, acc.y * din,
                                                acc.z * din, acc.w * din);
        }
        __syncthreads();  // handoff fence (uniform loop, barrier-legal)

        // m_j per lane, fast tanh into sT
        const int j = lane;
        float m = sb1[j];
        const float* a = sA[wid];
#pragma unroll
        for (int c = 0; c < NOBS; ++c) m = fmaf(a[c], sW1[c * NMID + j], m);
        sT[wid][j] = fast_tanh(m);
        __syncthreads();  // handoff fence

        // o_k: lane = jg*8 + k; 8-FMA partial over jj, reduce over jg
        float o = 0.f;
#pragma unroll
        for (int jj = 0; jj < 8; ++jj) {
            int jr = jg * 8 + jj;
            o = fmaf(sT[wid][jr], sW2p[jr * 9 + k], o);
        }
        o += __shfl_xor(o, 8);
        o += __shfl_xor(o, 16);
        o += __shfl_xor(o, 32);
        if (valid && jg == 0)
            out[(size_t)node * NACT + k] = o + sb2[k];
    }
}

extern "C" void kernel_launch(void* const* d_in, const int* in_sizes, int n_in,
                              void* d_out, int out_size, void* d_ws, size_t ws_size,
                              hipStream_t stream) {
    const float* x  = (const float*)d_in[0];
    const int*   ei = (const int*)d_in[1];
    const float* W1 = (const float*)d_in[2];
    const float* b1 = (const float*)d_in[3];
    const float* W2 = (const float*)d_in[4];
    const float* b2 = (const float*)d_in[5];
    float* out = (float*)d_out;

    const int n = in_sizes[0] / NOBS;       // 100000
    const long long e = in_sizes[1] / 2;    // 1600000
    const int B = (n + BNODES - 1) >> BSH;  // 782 buckets

    // ws layout (20.0 MB):
    //   gcnt int[1024] @0 | arena uint[B*CAP] @4096 | pk uint[n] | dinv f32[n]
    //   | y2 half2[n*16]
    char* ws = (char*)d_ws;
    int*          gcnt  = (int*)ws;
    unsigned int* arena = (unsigned int*)(ws + 4096);
    unsigned int* pk    = (unsigned int*)(ws + 4096 + (size_t)B * ARENA_B);
    float*        dinv  = (float*)(ws + 4096 + (size_t)B * ARENA_B + (size_t)n * 4);
    __half2*      y2    = (__half2*)(ws + 4096 + (size_t)B * ARENA_B + (size_t)n * 8);

    hipMemsetAsync(gcnt, 0, 4096, stream);
    int nsb = (int)((e + SPLIT_E - 1) / SPLIT_E);
    k_split<<<nsb, 256, 0, stream>>>(ei, gcnt, arena, e, B);
    k_sort<<<B, 256, 0, stream>>>(gcnt, arena, x, pk, dinv, y2, n);
    const int npb = 4 * NPW;  // nodes per block
    k_fused<<<(n + npb - 1) / npb, 256, 0, stream>>>(arena, pk, dinv, y2,
                                                     W1, b1, W2, b2, out, n);
}

// Round 10
// 99.803 us; speedup vs baseline: 4.1348x; 1.0465x over previous
//
#include <hip/hip_runtime.h>
#include <hip/hip_fp16.h>
#include <math.h>

// GCNConv QNet: out = tanh( (segsum(x[src]*norm, dst) + selfloop) @ W1 + b1 ) @ W2 + b2
// norm = dinv[src]*dinv[dst], dinv = rsqrt(in_degree + 1).
// Aggregation in 32-dim obs space (W1 applied AFTER segment_sum — linearity).
// R10: LDS-free, barrier-free k_fused epilogue — W1 column + W2 row in
// registers per lane, m-phase via v_readlane broadcast of the (already
// wave-replicated) agg, single wave-local fenced sT handoff for the o-phase.
// k_split holds its 16 edges/thread in registers (no ebuf/bbuf LDS).

#define NOBS 32
#define NMID 64
#define NACT 8
#define BSH 7
#define BNODES 128           // nodes per bucket
#define CAP 4096             // max entries per bucket (mean ~2046)
#define ARENA_B 16384        // bytes per bucket arena (= CAP*4)
#define SPLIT_E 4096         // edges per split block
#define NPW 4                // nodes per wave in k_fused

__device__ __forceinline__ bool edges_i64(const int* ei) {
    return (ei[1] | ei[3] | ei[5] | ei[7]) == 0;
}

// tanh(x) = 1 - 2/(1+e^{2x}); exact at +-inf, ~1e-5 rel err, branch-free.
__device__ __forceinline__ float fast_tanh(float x) {
    float t = __expf(2.f * x);
    return 1.f - 2.f * __builtin_amdgcn_rcpf(1.f + t);
}

__device__ __forceinline__ float rl(float v, int lane) {
    return __int_as_float(__builtin_amdgcn_readlane(__float_as_int(v), lane));
}

// Multisplit: bin 4096 edges by dst-bucket. Edges live in registers
// (16/thread); LDS only for the grouped output + counters (~25 KB).
__global__ __launch_bounds__(256) void k_split(
        const int* __restrict__ ei, int* __restrict__ gcnt,
        unsigned int* __restrict__ arena, long long e, int nbuckets) {
    __shared__ int sbuf[SPLIT_E];   // bucket-grouped entries (16 KB)
    __shared__ int offs[1024];
    __shared__ int cur[1024];
    __shared__ int tsum[256];
    const int tid = threadIdx.x;
    int eb[16];
    int bk[16];

    for (int b = tid; b < 1024; b += 256) cur[b] = 0;  // cur = hist
    __syncthreads();

    const long long base = (long long)blockIdx.x * SPLIT_E;
    const bool i64 = edges_i64(ei);
    const long long* e64 = (const long long*)ei;
#pragma unroll
    for (int j = 0; j < 8; ++j) {
        const int kk = j * 512 + tid * 2;
        const long long ge = base + kk;
        const bool v0 = ge < e, v1 = ge + 1 < e;
        int s0 = 0, d0 = 0, s1 = 0, d1 = 0;
        if (v1) {  // paired loads
            if (i64) {
                ulonglong2 sp = *(const ulonglong2*)(e64 + ge);
                ulonglong2 dp = *(const ulonglong2*)(e64 + e + ge);
                s0 = (int)sp.x; s1 = (int)sp.y; d0 = (int)dp.x; d1 = (int)dp.y;
            } else {
                int2 sp = *(const int2*)(ei + ge);
                int2 dp = *(const int2*)(ei + e + ge);
                s0 = sp.x; s1 = sp.y; d0 = dp.x; d1 = dp.y;
            }
        } else if (v0) {
            if (i64) { s0 = (int)e64[ge]; d0 = (int)e64[e + ge]; }
            else     { s0 = ei[ge];       d0 = ei[e + ge]; }
        }
        eb[2 * j]     = s0 | ((d0 & (BNODES - 1)) << 20);
        bk[2 * j]     = v0 ? (d0 >> BSH) : -1;
        eb[2 * j + 1] = s1 | ((d1 & (BNODES - 1)) << 20);
        bk[2 * j + 1] = v1 ? (d1 >> BSH) : -1;
        if (v0) atomicAdd(&cur[d0 >> BSH], 1);
        if (v1) atomicAdd(&cur[d1 >> BSH], 1);
    }
    __syncthreads();

    // exclusive scan of cur(=hist)[0..1024), 4 bins/thread
    const int t4 = tid * 4;
    int s0 = cur[t4], s1 = cur[t4 + 1], s2 = cur[t4 + 2], s3 = cur[t4 + 3];
    int my = s0 + s1 + s2 + s3;
    tsum[tid] = my;
    __syncthreads();
    for (int off = 1; off < 256; off <<= 1) {
        int t = (tid >= off) ? tsum[tid - off] : 0;
        __syncthreads();
        tsum[tid] += t;
        __syncthreads();
    }
    int ex = tsum[tid] - my;
    offs[t4] = ex;
    offs[t4 + 1] = ex + s0;
    offs[t4 + 2] = ex + s0 + s1;
    offs[t4 + 3] = ex + s0 + s1 + s2;
    __syncthreads();
    for (int b = tid; b < 1024; b += 256) cur[b] = offs[b];  // cursors
    __syncthreads();

    // scatter from registers into grouped sbuf
#pragma unroll
    for (int j = 0; j < 16; ++j) {
        if (bk[j] >= 0) {
            int slot = atomicAdd(&cur[bk[j]], 1);
            sbuf[slot] = eb[j];
        }
    }
    __syncthreads();

    // flush one run per thread (contiguous addresses -> L2 line merge)
    for (int b = tid; b < nbuckets; b += 256) {
        int beg = offs[b];
        int len = cur[b] - beg;
        if (len <= 0) continue;
        int g = atomicAdd(&gcnt[b], len);
        if (g >= CAP) continue;
        if (g + len > CAP) len = CAP - g;
        unsigned int* dst = arena + (size_t)b * CAP + g;
        for (int j = 0; j < len; ++j) dst[j] = (unsigned int)sbuf[beg + j];
    }
}

// In-bucket counting sort by dlocal -> node-contiguous runs. Emits
// pk[node] = beg|(cnt<<22), dinv, and fp16 prescaled y = x*dinv rows.
__global__ __launch_bounds__(256) void k_sort(
        const int* __restrict__ gcnt, unsigned int* __restrict__ arena,
        const float* __restrict__ x, unsigned int* __restrict__ pk,
        float* __restrict__ dinv, __half2* __restrict__ y2, int n) {
    __shared__ unsigned int sbuf[CAP];   // 16 KB
    __shared__ unsigned int obuf[CAP];   // 16 KB
    __shared__ int hist[BNODES];
    __shared__ int offs[BNODES];
    __shared__ int cur[BNODES];
    __shared__ float rinv[BNODES];
    const int b = blockIdx.x, tid = threadIdx.x;
    const int count = min(gcnt[b], CAP);
    unsigned int* ent = arena + (size_t)b * CAP;

    if (tid < BNODES) hist[tid] = 0;
    __syncthreads();
    for (int p = tid; p < count; p += 256) {
        unsigned int v = ent[p];
        sbuf[p] = v;
        atomicAdd(&hist[v >> 20], 1);
    }
    __syncthreads();
    if (tid < BNODES) offs[tid] = hist[tid];
    __syncthreads();
    for (int off = 1; off < BNODES; off <<= 1) {
        int t = 0;
        if (tid < BNODES && tid >= off) t = offs[tid - off];
        __syncthreads();
        if (tid < BNODES) offs[tid] += t;
        __syncthreads();
    }
    if (tid < BNODES) {
        int ex = offs[tid] - hist[tid];   // exclusive
        cur[tid] = ex;
        float r = rsqrtf((float)(hist[tid] + 1));
        rinv[tid] = r;
        int node = b * BNODES + tid;
        if (node < n) {
            pk[node] = (unsigned int)(b * CAP + ex) | ((unsigned int)hist[tid] << 22);
            dinv[node] = r;
        }
    }
    __syncthreads();
    for (int p = tid; p < count; p += 256) {
        unsigned int v = sbuf[p];
        int pos = atomicAdd(&cur[v >> 20], 1);
        obuf[pos] = v;
    }
    // y write overlaps the sort scatter (independent of obuf)
    for (int idx = tid; idx < BNODES * 16; idx += 256) {
        int node = b * BNODES + (idx >> 4);
        if (node >= n) break;
        float r = rinv[idx >> 4];
        float2 v = ((const float2*)x)[(size_t)node * 16 + (idx & 15)];
        y2[(size_t)node * 16 + (idx & 15)] = __floats2half2_rn(v.x * r, v.y * r);
    }
    __syncthreads();
    for (int p = tid; p < count; p += 256) ent[p] = obuf[p];
}

// Fused: wave handles NPW nodes, NO block barriers in the loop.
// Gather: 8 groups x 8 lanes, 16 row-loads in flight; xor-butterfly leaves
// the full agg slice replicated in EVERY lane (slice l = lane&7).
// m-phase: readlane broadcast + register W1 column (no LDS).
// o-phase: per-wave sT handoff with wave-local fence + register W2 row.
__global__ __launch_bounds__(256) void k_fused(
        const unsigned int* __restrict__ arena, const unsigned int* __restrict__ pk,
        const float* __restrict__ dinv, const __half2* __restrict__ y2,
        const float* __restrict__ W1, const float* __restrict__ b1,
        const float* __restrict__ W2, const float* __restrict__ b2,
        float* __restrict__ out, int n) {
    __shared__ float sT[4][NMID];        // per-wave tanh row (1 KB)
    const int tid = threadIdx.x;
    const int wid = tid >> 6;
    const int lane = tid & 63;
    const int g = lane >> 3, l = lane & 7;   // gather mapping
    const int jg = g, k = l;                 // epilogue mapping

    // per-lane weight registers (block-shared loads, L2-hot)
    float w1col[NOBS];
#pragma unroll
    for (int c = 0; c < NOBS; ++c) w1col[c] = W1[c * NMID + lane];
    float w2row[8];
#pragma unroll
    for (int jj = 0; jj < 8; ++jj) w2row[jj] = W2[(jg * 8 + jj) * NACT + k];
    const float b1v = b1[lane];
    const float b2v = b2[k];

    const int nodeBase = blockIdx.x * (4 * NPW) + wid * NPW;

    for (int nn = 0; nn < NPW; ++nn) {
        const int node = nodeBase + nn;       // wave-uniform
        const bool valid = node < n;          // wave-uniform

        float4 acc = make_float4(0.f, 0.f, 0.f, 0.f);
        float din = 0.f;
        int beg = 0, cnt = 0;
        if (valid) {
            din = dinv[node];
            unsigned int p = pk[node];
            beg = (int)(p & 0x3FFFFF);
            cnt = (int)(p >> 22);
        }
        if (valid && g == 0) {  // self-loop row
            uint2 sv = ((const uint2*)(y2 + (size_t)node * 16))[l];
            float2 f0 = __half22float2(*reinterpret_cast<const __half2*>(&sv.x));
            float2 f1 = __half22float2(*reinterpret_cast<const __half2*>(&sv.y));
            acc.x = f0.x; acc.y = f0.y; acc.z = f1.x; acc.w = f1.y;
        }
        const unsigned int* ent = arena + beg;
        int i = g;
        for (; i + 8 < cnt; i += 16) {
            unsigned int e0 = ent[i], e1 = ent[i + 8];
            uint2 v0 = ((const uint2*)(y2 + (size_t)(e0 & 0xFFFFF) * 16))[l];
            uint2 v1 = ((const uint2*)(y2 + (size_t)(e1 & 0xFFFFF) * 16))[l];
            float2 a0 = __half22float2(*reinterpret_cast<const __half2*>(&v0.x));
            float2 a1 = __half22float2(*reinterpret_cast<const __half2*>(&v0.y));
            float2 b0 = __half22float2(*reinterpret_cast<const __half2*>(&v1.x));
            float2 b1f = __half22float2(*reinterpret_cast<const __half2*>(&v1.y));
            acc.x += a0.x + b0.x; acc.y += a0.y + b0.y;
            acc.z += a1.x + b1f.x; acc.w += a1.y + b1f.y;
        }
        if (i < cnt) {
            unsigned int e0 = ent[i];
            uint2 v0 = ((const uint2*)(y2 + (size_t)(e0 & 0xFFFFF) * 16))[l];
            float2 a0 = __half22float2(*reinterpret_cast<const __half2*>(&v0.x));
            float2 a1 = __half22float2(*reinterpret_cast<const __half2*>(&v0.y));
            acc.x += a0.x; acc.y += a0.y; acc.z += a1.x; acc.w += a1.y;
        }
        // xor-butterfly over lane bits 3..5: ALL lanes end with the slice-l sum
        acc.x += __shfl_xor(acc.x, 8);  acc.y += __shfl_xor(acc.y, 8);
        acc.z += __shfl_xor(acc.z, 8);  acc.w += __shfl_xor(acc.w, 8);
        acc.x += __shfl_xor(acc.x, 16); acc.y += __shfl_xor(acc.y, 16);
        acc.z += __shfl_xor(acc.z, 16); acc.w += __shfl_xor(acc.w, 16);
        acc.x += __shfl_xor(acc.x, 32); acc.y += __shfl_xor(acc.y, 32);
        acc.z += __shfl_xor(acc.z, 32); acc.w += __shfl_xor(acc.w, 32);
        acc.x *= din; acc.y *= din; acc.z *= din; acc.w *= din;

        // m-phase: lane s (s<8) holds channels 4s..4s+3 -> readlane broadcast
        float m = b1v;
#pragma unroll
        for (int s = 0; s < 8; ++s) {
            m = fmaf(rl(acc.x, s), w1col[4 * s + 0], m);
            m = fmaf(rl(acc.y, s), w1col[4 * s + 1], m);
            m = fmaf(rl(acc.z, s), w1col[4 * s + 2], m);
            m = fmaf(rl(acc.w, s), w1col[4 * s + 3], m);
        }
        sT[wid][lane] = fast_tanh(m);
        // wave-local handoff fence: DS write completed + no compiler reorder
        asm volatile("s_waitcnt lgkmcnt(0)" ::: "memory");
        __builtin_amdgcn_sched_barrier(0);

        // o-phase: 8 ds_read (2-way conflict max) + 8 FMA + 3-step reduce
        float o = 0.f;
#pragma unroll
        for (int jj = 0; jj < 8; ++jj)
            o = fmaf(sT[wid][jg * 8 + jj], w2row[jj], o);
        o += __shfl_xor(o, 8);
        o += __shfl_xor(o, 16);
        o += __shfl_xor(o, 32);
        if (valid && jg == 0)
            out[(size_t)node * NACT + k] = o + b2v;
    }
}

extern "C" void kernel_launch(void* const* d_in, const int* in_sizes, int n_in,
                              void* d_out, int out_size, void* d_ws, size_t ws_size,
                              hipStream_t stream) {
    const float* x  = (const float*)d_in[0];
    const int*   ei = (const int*)d_in[1];
    const float* W1 = (const float*)d_in[2];
    const float* b1 = (const float*)d_in[3];
    const float* W2 = (const float*)d_in[4];
    const float* b2 = (const float*)d_in[5];
    float* out = (float*)d_out;

    const int n = in_sizes[0] / NOBS;       // 100000
    const long long e = in_sizes[1] / 2;    // 1600000
    const int B = (n + BNODES - 1) >> BSH;  // 782 buckets

    // ws layout (20.0 MB):
    //   gcnt int[1024] @0 | arena uint[B*CAP] @4096 | pk uint[n] | dinv f32[n]
    //   | y2 half2[n*16]
    char* ws = (char*)d_ws;
    int*          gcnt  = (int*)ws;
    unsigned int* arena = (unsigned int*)(ws + 4096);
    unsigned int* pk    = (unsigned int*)(ws + 4096 + (size_t)B * ARENA_B);
    float*        dinv  = (float*)(ws + 4096 + (size_t)B * ARENA_B + (size_t)n * 4);
    __half2*      y2    = (__half2*)(ws + 4096 + (size_t)B * ARENA_B + (size_t)n * 8);

    hipMemsetAsync(gcnt, 0, 4096, stream);
    int nsb = (int)((e + SPLIT_E - 1) / SPLIT_E);
    k_split<<<nsb, 256, 0, stream>>>(ei, gcnt, arena, e, B);
    k_sort<<<B, 256, 0, stream>>>(gcnt, arena, x, pk, dinv, y2, n);
    const int npb = 4 * NPW;  // nodes per block
    k_fused<<<(n + npb - 1) / npb, 256, 0, stream>>>(arena, pk, dinv, y2,
                                                     W1, b1, W2, b2, out, n);
}